// Round 6
// baseline (2811.490 us; speedup 1.0000x reference)
//
#include <hip/hip_runtime.h>
#include <stdint.h>

#define B_ 256
#define T_ 512
#define F_ 128
#define U_ 256
#define H_ 64
#define G4U (4 * U_)

typedef __attribute__((ext_vector_type(8))) short short8;
typedef __attribute__((ext_vector_type(4))) float f32x4;
typedef unsigned long long ull;

// LDS-only barrier: NO vmcnt drain (publish/seq stores stay in flight).
#define BARRIER_LDS() asm volatile("s_waitcnt lgkmcnt(0)\ns_barrier" ::: "memory")

__device__ __forceinline__ uint16_t f2bf(float f) {
  uint32_t u = __builtin_bit_cast(uint32_t, f);
  u += 0x7fffu + ((u >> 16) & 1u);
  return (uint16_t)(u >> 16);
}
__device__ __forceinline__ float sigm(float z) {
  return 1.0f / (1.0f + __expf(-z));
}
__device__ __forceinline__ ull ald(const ull* p) {
  return __hip_atomic_load(p, __ATOMIC_RELAXED, __HIP_MEMORY_SCOPE_AGENT);
}

// ---------------------------------------------------------------------------
// Persistent LSTM, PAIRWISE exchange topology (R5 lesson: 8-WG fan-out pays
// multi-peer skew x IF round trips; fix the topology, not the poll).
// 32 WGs x 256 threads (4 waves, 1/SIMD). Group bg∈[0,16): 16 batch rows.
// Member m∈{0,1} owns units [m*128,(m+1)*128) -> 512 gate-cols in VGPRs
// (rec [256x512] + kern [128x512] bf16 ~ 384 regs/wave).
// blockIdx = bg + 16*m -> pair lands on SAME XCD (round-robin heuristic),
// exchange through shared L2 (perf only; agent-scope atomics keep it
// correct on any placement).
// Column assignment ctg = wv*2+d+8*q puts ALL 4 GATES of a unit in one
// lane's accumulators -> gates fully in registers, no z LDS, 2 barriers.
// Exchange: tagged words {h[u][r], h[u+16][r] | tag t+1}, 2-slot parity.
// ---------------------------------------------------------------------------
__global__ __launch_bounds__(256, 1) void lstm_kernel(
    const float* __restrict__ x, const float* __restrict__ kern,
    const float* __restrict__ rker, const float* __restrict__ bias,
    uint16_t* __restrict__ seq, ull* __restrict__ hbuf)
{
  const int tid  = threadIdx.x;
  const int lane = tid & 63;
  const int wv   = tid >> 6;
  const int il   = lane & 15;
  const int rg   = lane >> 4;
  const int bg   = blockIdx.x & 15;
  const int m    = blockIdx.x >> 4;

  // A-fragment staging: [kt][lane][8]; frag read = ds_read_b128 at lane*16.
  __shared__ __align__(16) uint16_t x_stage[4][64][8];      // 4 KB
  __shared__ __align__(16) uint16_t h_stage[2][8][64][8];   // 16 KB (parity)

  // ---- weights as B-fragments: ctg = wv*2 + d + 8*q, cols c = ctg*16+il ----
  short8 wf[4][2][8];   // [gate q][d][ktile]  K=256
  short8 kf[4][2][4];   // [gate q][d][ktile]  K=128
  float  bias_r[4][2];
  #pragma unroll
  for (int q = 0; q < 4; ++q)
    #pragma unroll
    for (int d = 0; d < 2; ++d) {
      const int ul   = (wv * 2 + d) * 16 + il;        // member-local unit
      const int gcol = q * U_ + m * 128 + ul;         // i|f|g|o blocks of 256
      bias_r[q][d] = bias[gcol];
      #pragma unroll
      for (int kt = 0; kt < 8; ++kt) {
        short8 v;
        #pragma unroll
        for (int j = 0; j < 8; ++j)
          v[j] = (short)f2bf(rker[(size_t)(kt * 32 + rg * 8 + j) * G4U + gcol]);
        wf[q][d][kt] = v;
      }
      #pragma unroll
      for (int kt = 0; kt < 4; ++kt) {
        short8 v;
        #pragma unroll
        for (int j = 0; j < 8; ++j)
          v[j] = (short)f2bf(kern[(size_t)(kt * 32 + rg * 8 + j) * G4U + gcol]);
        kf[q][d][kt] = v;
      }
    }

  // x-staging role (8 floats/thread, flat-contiguous LDS write)
  const int xrow = tid & 15;
  const int xfb  = (tid >> 6) * 32 + ((tid >> 4) & 3) * 8;

  // own/peer unit constants
  const int Ua = m * 128 + wv * 32 + il;          // d=0 unit (global)
  const int kta = Ua >> 5, posa = Ua & 7, ga = ((Ua & 31) >> 3) * 16;
  const int posb = (Ua + 16) & 7, gb = (((Ua + 16) & 31) >> 3) * 16;  // ktb==kta

  ull* const pub   = hbuf + ((size_t)(bg * 2 + m) * 2) * 1024;
  const ull* const peer = hbuf + ((size_t)(bg * 2 + (1 - m)) * 2) * 1024;

  float cst[2][4];
  #pragma unroll
  for (int d = 0; d < 2; ++d)
    #pragma unroll
    for (int j = 0; j < 4; ++j) cst[d][j] = 0.f;

  // ---- stage x for t=0 ----
  float xp[8];
  {
    const float* p = x + ((size_t)(bg * 16 + xrow) * T_ + 0) * F_ + xfb;
    #pragma unroll
    for (int j = 0; j < 8; ++j) xp[j] = p[j];
    uint16_t* d = (uint16_t*)x_stage + tid * 8;
    #pragma unroll
    for (int j = 0; j < 8; ++j) d[j] = f2bf(xp[j]);
  }
  __syncthreads();

  for (int t = 0; t < T_; ++t) {
    // (A) issue peer poll loads EARLY (latency overlaps x-MFMA)
    ull pv[4];
    const ull* pp = peer + (size_t)((t - 1) & 1) * 1024 + tid * 4;
    if (t > 0) {
      #pragma unroll
      for (int k = 0; k < 4; ++k) pv[k] = ald(pp + k);
    }
    // x-part: z = bias + x_t @ kernel
    f32x4 acc[4][2];
    #pragma unroll
    for (int q = 0; q < 4; ++q)
      #pragma unroll
      for (int d = 0; d < 2; ++d)
        acc[q][d] = (f32x4){bias_r[q][d], bias_r[q][d], bias_r[q][d], bias_r[q][d]};
    #pragma unroll
    for (int kt = 0; kt < 4; ++kt) {
      short8 a = *(const short8*)&x_stage[kt][lane][0];
      #pragma unroll
      for (int q = 0; q < 4; ++q)
        #pragma unroll
        for (int d = 0; d < 2; ++d)
          acc[q][d] = __builtin_amdgcn_mfma_f32_16x16x32_bf16(a, kf[q][d][kt], acc[q][d], 0, 0, 0);
    }
    // x prefetch for t+1
    {
      const int tn = (t + 1 < T_) ? t + 1 : t;
      const float* p = x + ((size_t)(bg * 16 + xrow) * T_ + tn) * F_ + xfb;
      #pragma unroll
      for (int j = 0; j < 8; ++j) xp[j] = p[j];
    }
    if (t > 0) {
      // (B) single-peer poll: retry-all (coalesced), 1-2 rounds typical
      const uint32_t expt = (uint32_t)t;
      for (;;) {
        bool ok = ((uint32_t)(pv[0] >> 32) == expt) & ((uint32_t)(pv[1] >> 32) == expt)
                & ((uint32_t)(pv[2] >> 32) == expt) & ((uint32_t)(pv[3] >> 32) == expt);
        if (ok) break;
        #pragma unroll
        for (int k = 0; k < 4; ++k) pv[k] = ald(pp + k);
      }
      // unpack peer half into h_stage[(t-1)&1]
      const int ss = (t - 1) & 1;
      const int r  = tid >> 4;                 // word row (const per thread)
      #pragma unroll
      for (int k = 0; k < 4; ++k) {
        const int q  = (tid & 15) * 4 + k;     // wv_p*16 + il_p
        const int Up = (1 - m) * 128 + (q >> 4) * 32 + (q & 15);
        const int Uq = Up + 16;
        h_stage[ss][Up >> 5][(((Up & 31) >> 3) * 16) + r][Up & 7] = (uint16_t)pv[k];
        h_stage[ss][Uq >> 5][(((Uq & 31) >> 3) * 16) + r][Uq & 7] = (uint16_t)(pv[k] >> 16);
      }
    }
    BARRIER_LDS();   // (BAR1) peer h_stage ready; also guards x_stage RAW->WAR
    if (t > 0) {
      const int ss = (t - 1) & 1;
      #pragma unroll
      for (int kt = 0; kt < 8; ++kt) {
        short8 a = *(const short8*)&h_stage[ss][kt][lane][0];
        #pragma unroll
        for (int q = 0; q < 4; ++q)
          #pragma unroll
          for (int d = 0; d < 2; ++d)
            acc[q][d] = __builtin_amdgcn_mfma_f32_16x16x32_bf16(a, wf[q][d][kt], acc[q][d], 0, 0, 0);
      }
    }
    // (C) gates fully in registers (lane holds i,f,g,o of its own units)
    float hh[2][4];
    #pragma unroll
    for (int d = 0; d < 2; ++d)
      #pragma unroll
      for (int j = 0; j < 4; ++j) {
        const float zi = acc[0][d][j], zf = acc[1][d][j];
        const float zg = acc[2][d][j], zo = acc[3][d][j];
        const float ii = sigm(zi), ff = sigm(zf);
        const float gg = zg * sigm(zg), oo = sigm(zo);
        const float c  = ff * cst[d][j] + ii * gg;
        cst[d][j] = c;
        hh[d][j]  = oo * (c * sigm(c));
      }
    // (E) tagged publish + own-h -> LDS + seq + x_stage(t+1)
    {
      const int s2 = t & 1;
      ull* pw = pub + (size_t)s2 * 1024;
      #pragma unroll
      for (int j = 0; j < 4; ++j) {
        const int r = rg * 4 + j;
        const uint16_t b0 = f2bf(hh[0][j]), b1 = f2bf(hh[1][j]);
        const uint32_t packed = (uint32_t)b0 | ((uint32_t)b1 << 16);
        __hip_atomic_store(pw + (r * 64 + wv * 16 + il),
                           (ull)packed | ((ull)(uint32_t)(t + 1) << 32),
                           __ATOMIC_RELAXED, __HIP_MEMORY_SCOPE_AGENT);
        h_stage[s2][kta][ga + r][posa] = b0;
        h_stage[s2][kta][gb + r][posb] = b1;
        uint16_t* sp = seq + ((size_t)(bg * 16 + r) * T_ + t) * U_;
        sp[Ua] = b0; sp[Ua + 16] = b1;
      }
      uint16_t* xd = (uint16_t*)x_stage + tid * 8;
      #pragma unroll
      for (int j = 0; j < 8; ++j) xd[j] = f2bf(xp[j]);
    }
    BARRIER_LDS();   // (BAR2) x_stage + own-h writes visible for next step
  }
}

// ---------------------------------------------------------------------------
// Head GEMM: partials[g][b][h] = seq[b, g-chunk] @ w_out[g-chunk, h]
// ---------------------------------------------------------------------------
__global__ __launch_bounds__(256, 1) void head_kernel(
    const uint16_t* __restrict__ seq, const float* __restrict__ w_out,
    float* __restrict__ partials)
{
  const int g    = blockIdx.x;
  const int tid  = threadIdx.x;
  const int lane = tid & 63;
  const int wv   = tid >> 6;

  f32x4 acc[4][4];
  #pragma unroll
  for (int i = 0; i < 4; ++i)
    #pragma unroll
    for (int c = 0; c < 4; ++c) acc[i][c] = (f32x4){0.f, 0.f, 0.f, 0.f};

  for (int ks = 0; ks < 64; ++ks) {
    const int krow = g * 2048 + ks * 32 + (lane >> 4) * 8;
    short8 bf[4];
    #pragma unroll
    for (int c = 0; c < 4; ++c) {
      short8 v;
      #pragma unroll
      for (int j = 0; j < 8; ++j)
        v[j] = (short)f2bf(w_out[(size_t)(krow + j) * H_ + c * 16 + (lane & 15)]);
      bf[c] = v;
    }
    #pragma unroll
    for (int i = 0; i < 4; ++i) {
      const int b = (wv * 4 + i) * 16 + (lane & 15);
      short8 a = *(const short8*)(seq + (size_t)b * (T_ * U_) + krow);
      #pragma unroll
      for (int c = 0; c < 4; ++c)
        acc[i][c] = __builtin_amdgcn_mfma_f32_16x16x32_bf16(a, bf[c], acc[i][c], 0, 0, 0);
    }
  }
  #pragma unroll
  for (int i = 0; i < 4; ++i)
    #pragma unroll
    for (int c = 0; c < 4; ++c)
      #pragma unroll
      for (int r = 0; r < 4; ++r) {
        const int b = wv * 64 + i * 16 + (lane >> 4) * 4 + r;
        partials[((size_t)g * B_ + b) * H_ + c * 16 + (lane & 15)] = acc[i][c][r];
      }
}

__global__ void reduce_kernel(const float* __restrict__ partials,
                              const float* __restrict__ b_out,
                              float* __restrict__ out)
{
  const int i = blockIdx.x * 256 + threadIdx.x;   // b*64 + h
  float s = b_out[i & (H_ - 1)];
  #pragma unroll 8
  for (int g = 0; g < 64; ++g) s += partials[(size_t)g * (B_ * H_) + i];
  out[i] = s;
}

// ---------------------------------------------------------------------------
extern "C" void kernel_launch(void* const* d_in, const int* in_sizes, int n_in,
                              void* d_out, int out_size, void* d_ws, size_t ws_size,
                              hipStream_t stream) {
  (void)in_sizes; (void)n_in; (void)out_size; (void)ws_size;
  const float* x     = (const float*)d_in[0];
  const float* kern  = (const float*)d_in[1];
  const float* rker  = (const float*)d_in[2];
  const float* bias  = (const float*)d_in[3];
  const float* w_out = (const float*)d_in[4];
  const float* b_out = (const float*)d_in[5];
  float* out = (float*)d_out;

  char* ws = (char*)d_ws;
  const size_t seq_bytes  = (size_t)B_ * T_ * U_ * 2;            // 64 MB
  const size_t hbuf_bytes = (size_t)16 * 2 * 2 * 1024 * 8;       // 512 KB tagged
  uint16_t* seq      = (uint16_t*)ws;
  ull*      hbuf     = (ull*)(ws + seq_bytes);
  float*    partials = (float*)(ws + seq_bytes + hbuf_bytes);    // 4 MB

  // per-launch re-init: stale tags from a previous graph replay WOULD false-
  // match near t=T (tags cycle 1..512) -> zero the tagged buffer every launch.
  hipMemsetAsync(hbuf, 0, hbuf_bytes, stream);

  lstm_kernel<<<32, 256, 0, stream>>>(x, kern, rker, bias, seq, hbuf);
  head_kernel<<<64, 256, 0, stream>>>(seq, w_out, partials);
  reduce_kernel<<<64, 256, 0, stream>>>(partials, b_out, out);
}